// Round 1
// baseline (503.226 us; speedup 1.0000x reference)
//
#include <hip/hip_runtime.h>
#include <math.h>

#define Bsz 8
#define Nsz 1024
#define FIN 128
#define Hh  4
#define FO  64
#define COLS 256   // Hh*FO
#define TN  16
#define TM  32

// ---------------- Kernel A: h = x@W, e_src, e_dst ----------------
// grid: (B*N/16) = 512 blocks, 256 threads. Block handles 16 rows of n.
// thread j owns output column j (head = j>>6, f = j&63).
__global__ __launch_bounds__(256) void gat_proj(
    const float* __restrict__ x, const float* __restrict__ W,
    const float* __restrict__ a, float* __restrict__ h_g,
    float* __restrict__ es_g, float* __restrict__ ed_g)
{
    __shared__ float x_lds[16 * FIN];       // 8 KB
    const int j   = threadIdx.x;
    const int blk = blockIdx.x;             // 0..511
    const int b   = blk >> 6;
    const int n0  = (blk & 63) * 16;
    const long rowb = (long)b * Nsz + n0;

    // load 16x128 x-tile (512 float4)
    const float4* xg4 = (const float4*)(x + rowb * FIN);
    float4* xl4 = (float4*)x_lds;
    xl4[j]       = xg4[j];
    xl4[j + 256] = xg4[j + 256];
    __syncthreads();

    float hv[16];
    #pragma unroll
    for (int r = 0; r < 16; r++) hv[r] = 0.f;

    const float* Wc = W + j;                // column j, stride COLS
    for (int k4 = 0; k4 < FIN / 4; k4++) {
        float w0 = Wc[(k4*4 + 0) * COLS];
        float w1 = Wc[(k4*4 + 1) * COLS];
        float w2 = Wc[(k4*4 + 2) * COLS];
        float w3 = Wc[(k4*4 + 3) * COLS];
        #pragma unroll
        for (int r = 0; r < 16; r++) {
            float4 xv = xl4[r * (FIN/4) + k4];   // wave-uniform broadcast
            hv[r] = fmaf(xv.x, w0, fmaf(xv.y, w1, fmaf(xv.z, w2, fmaf(xv.w, w3, hv[r]))));
        }
    }

    const int w = j >> 6, f = j & 63;       // head, feature
    const float as = a[w * (2*FO) + f];
    const float ad = a[w * (2*FO) + FO + f];
    #pragma unroll
    for (int r = 0; r < 16; r++) {
        h_g[(rowb + r) * COLS + j] = hv[r];
        float s1 = hv[r] * as;
        float s2 = hv[r] * ad;
        #pragma unroll
        for (int off = 32; off > 0; off >>= 1) {
            s1 += __shfl_xor(s1, off, 64);
            s2 += __shfl_xor(s2, off, 64);
        }
        if (f == 0) {
            es_g[(rowb + r) * Hh + w] = s1;
            ed_g[(rowb + r) * Hh + w] = s2;
        }
    }
}

// ---------------- Kernel B: flash-style masked softmax + aggregate ----------------
// grid: (N/TN, B) = (64, 8), 256 threads.
// Phase S: wave w owns rows {4w..4w+3}; half-wave hh owns heads {2hh, 2hh+1}; lane&31 = mi.
// Phase A: wave w owns head w; lane = f; 16 rows accumulated in registers.
__global__ __launch_bounds__(256) void gat_attn(
    const int* __restrict__ adj, const float* __restrict__ h_g,
    const float* __restrict__ es_g, const float* __restrict__ ed_g,
    float* __restrict__ out)
{
    __shared__ float h_lds[TM * COLS];        // 32 KB
    __shared__ float p_lds[TN * Hh * TM];     // 8 KB
    __shared__ float o_lds[Hh * TN * FO];     // 16 KB
    __shared__ int   adj_lds[TN * TM];        // 2 KB
    __shared__ float ed_lds[TM * Hh];         // 512 B
    __shared__ float al_lds[TN * Hh];
    __shared__ float l_lds[TN * Hh];
    __shared__ float es_lds[TN * Hh];

    const int j    = threadIdx.x;
    const int w    = j >> 6;                  // wave id
    const int lane = j & 63;
    const int b    = blockIdx.y;
    const int n0   = blockIdx.x * TN;
    const long rowb = (long)b * Nsz + n0;

    if (j < TN * Hh) es_lds[j] = es_g[rowb * Hh + j];

    const int mi = lane & (TM - 1);
    const int hh = lane >> 5;                 // 0/1 half-wave

    float m_run[4][2], l_run[4][2];
    #pragma unroll
    for (int r4 = 0; r4 < 4; r4++)
        #pragma unroll
        for (int ii = 0; ii < 2; ii++) { m_run[r4][ii] = -INFINITY; l_run[r4][ii] = 0.f; }

    float acc[TN];
    #pragma unroll
    for (int r = 0; r < TN; r++) acc[r] = 0.f;

    __syncthreads();
    float es[4][2];
    #pragma unroll
    for (int r4 = 0; r4 < 4; r4++)
        #pragma unroll
        for (int ii = 0; ii < 2; ii++)
            es[r4][ii] = es_lds[(w*4 + r4) * Hh + hh*2 + ii];

    for (int t = 0; t < Nsz / TM; t++) {
        const int m0 = t * TM;
        // ---- cooperative loads ----
        {
            const float4* hg4 = (const float4*)(h_g + ((long)b * Nsz + m0) * COLS);
            float4* hl4 = (float4*)h_lds;
            #pragma unroll
            for (int c = 0; c < (TM * COLS / 4) / 256; c++)   // 8 float4 per thread
                hl4[j + c * 256] = hg4[j + c * 256];
            if (j < 128) {
                const int r = j >> 3, ch = j & 7;             // 16 rows x 8 int4
                const int4* ag4 = (const int4*)(adj + (rowb + r) * Nsz + m0);
                ((int4*)adj_lds)[r * 8 + ch] = ag4[ch];
            } else {
                const int t2 = j - 128;                       // 32*4 e_dst values
                ed_lds[t2] = ed_g[((long)b * Nsz + m0) * Hh + t2];
            }
        }
        __syncthreads();
        // ---- phase S: online softmax weights ----
        #pragma unroll
        for (int r4 = 0; r4 < 4; r4++) {
            const int r = w * 4 + r4;
            const int av = adj_lds[r * TM + mi];
            #pragma unroll
            for (int ii = 0; ii < 2; ii++) {
                const int hx = hh * 2 + ii;
                float s = es[r4][ii] + ed_lds[mi * Hh + hx];
                s = s > 0.f ? s : 0.2f * s;
                s = av > 0 ? s : -9e15f;
                float mt = s;
                #pragma unroll
                for (int off = 16; off > 0; off >>= 1)
                    mt = fmaxf(mt, __shfl_xor(mt, off, 64));
                const float mo = m_run[r4][ii];
                const float mn = fmaxf(mo, mt);
                const float alpha = __expf(mo - mn);          // -INF init -> 0
                const float p = __expf(s - mn);               // masked -> 0 (or 1 if row all-masked)
                float ps = p;
                #pragma unroll
                for (int off = 16; off > 0; off >>= 1)
                    ps += __shfl_xor(ps, off, 64);
                m_run[r4][ii] = mn;
                l_run[r4][ii] = l_run[r4][ii] * alpha + ps;
                p_lds[(r * Hh + hx) * TM + mi] = p;
                if (mi == 0) al_lds[r * Hh + hx] = alpha;
            }
        }
        __syncthreads();
        // ---- phase A: acc[r] = acc[r]*alpha + p . h ----
        {
            float hvv[TM];
            #pragma unroll
            for (int m = 0; m < TM; m++) hvv[m] = h_lds[m * COLS + j];
            #pragma unroll
            for (int r = 0; r < TN; r++) {
                float accv = acc[r] * al_lds[r * Hh + w];
                const float4* p4 = (const float4*)(p_lds + (r * Hh + w) * TM);
                #pragma unroll
                for (int m4 = 0; m4 < TM / 4; m4++) {
                    const float4 p = p4[m4];                  // wave-uniform broadcast
                    accv = fmaf(p.x, hvv[m4*4 + 0], accv);
                    accv = fmaf(p.y, hvv[m4*4 + 1], accv);
                    accv = fmaf(p.z, hvv[m4*4 + 2], accv);
                    accv = fmaf(p.w, hvv[m4*4 + 3], accv);
                }
                acc[r] = accv;
            }
        }
        __syncthreads();
    }

    // ---- epilogue: divide by l, mean over heads ----
    if (mi == 0) {
        #pragma unroll
        for (int r4 = 0; r4 < 4; r4++)
            #pragma unroll
            for (int ii = 0; ii < 2; ii++)
                l_lds[(w*4 + r4) * Hh + hh*2 + ii] = l_run[r4][ii];
    }
    __syncthreads();
    #pragma unroll
    for (int r = 0; r < TN; r++)
        o_lds[(w * TN + r) * FO + lane] = acc[r] / l_lds[r * Hh + w] * 0.25f;
    __syncthreads();
    {
        const int f2 = j & 63, rb = j >> 6;
        #pragma unroll
        for (int i = 0; i < 4; i++) {
            const int r = i * 4 + rb;
            const float sum = o_lds[(0*TN + r) * FO + f2] + o_lds[(1*TN + r) * FO + f2]
                            + o_lds[(2*TN + r) * FO + f2] + o_lds[(3*TN + r) * FO + f2];
            out[(rowb + r) * FO + f2] = sum;
        }
    }
}

extern "C" void kernel_launch(void* const* d_in, const int* in_sizes, int n_in,
                              void* d_out, int out_size, void* d_ws, size_t ws_size,
                              hipStream_t stream) {
    const float* x   = (const float*)d_in[0];   // (8,1024,128) f32
    const int*   adj = (const int*)d_in[1];     // (8,1024,1024) i32
    const float* W   = (const float*)d_in[2];   // (128,256) f32
    const float* a   = (const float*)d_in[3];   // (4,128) f32
    float* out = (float*)d_out;                 // (8,1024,64) f32

    // workspace: h (8MB) | e_src (128KB) | e_dst (128KB)
    float* h_g  = (float*)d_ws;
    float* es_g = h_g + (long)Bsz * Nsz * COLS;
    float* ed_g = es_g + (long)Bsz * Nsz * Hh;

    gat_proj<<<dim3(Bsz * Nsz / 16), dim3(256), 0, stream>>>(x, W, a, h_g, es_g, ed_g);
    gat_attn<<<dim3(Nsz / TN, Bsz), dim3(256), 0, stream>>>(adj, h_g, es_g, ed_g, out);
}

// Round 2
// 134.522 us; speedup vs baseline: 3.7409x; 3.7409x over previous
//
#include <hip/hip_runtime.h>
#include <math.h>

#define Bsz 8
#define Nsz 1024
#define FIN 128
#define Hh  4
#define FO  64
#define COLS 256   // Hh*FO
#define TN  16
#define TM  32
#define BN  (Bsz*Nsz)
#define SHIFT 12.0f

typedef __attribute__((ext_vector_type(8))) short short8;
typedef __attribute__((ext_vector_type(4))) float f32x4;

static __device__ inline ushort f2bf(float f) {           // RNE float->bf16
    uint u = __float_as_uint(f);
    u += 0x7FFFu + ((u >> 16) & 1u);
    return (ushort)(u >> 16);
}
static __device__ inline float bf2f(ushort h) { return __uint_as_float(((uint)h) << 16); }

// ---------------- Kernel A: h = x@W (bf16, tiled-transposed), e_src, e_dst ----------------
// grid: 512 blocks, 256 threads; block = 16 rows of n; thread j = output column j.
// h_gB layout: [b][mt=n/32][c=256][k=n%32] bf16  -> B-fragment reads in kernel B are
// single ds_read_b128 and the global stage is lane-contiguous 16B.
__global__ __launch_bounds__(256) void gat_proj(
    const float* __restrict__ x, const float* __restrict__ W,
    const float* __restrict__ a, ushort* __restrict__ h_gB,
    float* __restrict__ es_g, float* __restrict__ ed_g)
{
    __shared__ float x_lds[16 * FIN];       // 8 KB
    const int j   = threadIdx.x;
    const int blk = blockIdx.x;
    const int b   = blk >> 6;
    const int n0  = (blk & 63) * 16;
    const long rowb = (long)b * Nsz + n0;

    const float4* xg4 = (const float4*)(x + rowb * FIN);
    float4* xl4 = (float4*)x_lds;
    xl4[j]       = xg4[j];
    xl4[j + 256] = xg4[j + 256];
    __syncthreads();

    float hv[16];
    #pragma unroll
    for (int r = 0; r < 16; r++) hv[r] = 0.f;

    const float* Wc = W + j;
    for (int k4 = 0; k4 < FIN / 4; k4++) {
        float w0 = Wc[(k4*4 + 0) * COLS];
        float w1 = Wc[(k4*4 + 1) * COLS];
        float w2 = Wc[(k4*4 + 2) * COLS];
        float w3 = Wc[(k4*4 + 3) * COLS];
        #pragma unroll
        for (int r = 0; r < 16; r++) {
            float4 xv = xl4[r * (FIN/4) + k4];   // wave-uniform broadcast
            hv[r] = fmaf(xv.x, w0, fmaf(xv.y, w1, fmaf(xv.z, w2, fmaf(xv.w, w3, hv[r]))));
        }
    }

    // bf16 h in [b][mt][c][kin] layout: 32B contiguous per thread
    {
        const int mt = n0 >> 5, kin0 = n0 & 31;
        union { ushort u[16]; int4 v4[2]; } pk;
        #pragma unroll
        for (int r = 0; r < 16; r++) pk.u[r] = f2bf(hv[r]);
        int4* dst = (int4*)(h_gB + (((long)(b*32 + mt) * 256 + j) * 32 + kin0));
        dst[0] = pk.v4[0]; dst[1] = pk.v4[1];
    }

    const int w = j >> 6, f = j & 63;       // head = wave, feature = lane
    const float as = a[w * (2*FO) + f];
    const float ad = a[w * (2*FO) + FO + f];
    #pragma unroll
    for (int r = 0; r < 16; r++) {
        float s1 = hv[r] * as;
        float s2 = hv[r] * ad;
        #pragma unroll
        for (int off = 32; off > 0; off >>= 1) {
            s1 += __shfl_xor(s1, off, 64);
            s2 += __shfl_xor(s2, off, 64);
        }
        if (f == 0) {                       // transposed [h][b*N+n]
            es_g[(long)w * BN + rowb + r] = s1;
            ed_g[(long)w * BN + rowb + r] = s2;
        }
    }
}

// ---------------- Kernel B: masked softmax (fixed-shift) + MFMA aggregate ----------------
// grid: (N/TN=64, B=8), 256 threads. Phase S: wave w owns rows {4w..4w+3}, half-waves own
// head pairs, lane&31 = m index. Phase A: wave w = head w; 16x64 output via 4 MFMAs/tile.
__global__ __launch_bounds__(256, 4) void gat_attn(
    const int* __restrict__ adj, const ushort* __restrict__ h_gB,
    const float* __restrict__ es_g, const float* __restrict__ ed_g,
    float* __restrict__ out)
{
    __shared__ ushort hT[TM * COLS];        // 16 KB bf16 [c][k]; reused as o_lds (fp32) in epilogue
    __shared__ ushort p_bf[TN * Hh * TM];   // 4 KB bf16, A-fragment order [r][hx][m]
    __shared__ float  l_lds[TN * Hh];       // 256 B

    const int j    = threadIdx.x;
    const int w    = j >> 6;
    const int lane = j & 63;
    const int quad = lane >> 4;
    const int n16  = lane & 15;
    const int mi   = lane & 31;
    const int hh   = lane >> 5;
    const int b    = blockIdx.y;
    const int n0   = blockIdx.x * TN;
    const long rowb = (long)b * Nsz + n0;

    // e_src for this wave's 4 rows x this half-wave's 2 heads (broadcast loads, L2-hot)
    float es[4][2];
    #pragma unroll
    for (int r4 = 0; r4 < 4; r4++)
        #pragma unroll
        for (int ii = 0; ii < 2; ii++)
            es[r4][ii] = es_g[(long)(hh*2 + ii) * BN + rowb + w*4 + r4];

    f32x4 acc[4];
    #pragma unroll
    for (int c4 = 0; c4 < 4; c4++)
        #pragma unroll
        for (int r = 0; r < 4; r++) acc[c4][r] = 0.f;

    float l_part[4][2];
    #pragma unroll
    for (int r4 = 0; r4 < 4; r4++) { l_part[r4][0] = 0.f; l_part[r4][1] = 0.f; }

    short8 hreg[4]; int areg[4]; float edreg[2];
    const short8* hb8 = (const short8*)h_gB;
    #define PREFETCH(t)                                                             \
        {                                                                           \
            const short8* g = hb8 + (long)(b*32 + (t)) * 1024;                      \
            hreg[0] = g[j]; hreg[1] = g[j+256]; hreg[2] = g[j+512]; hreg[3] = g[j+768]; \
            const int m0p = (t) * TM;                                               \
            _Pragma("unroll")                                                       \
            for (int r4 = 0; r4 < 4; r4++)                                          \
                areg[r4] = adj[(rowb + w*4 + r4) * (long)Nsz + m0p + mi];           \
            _Pragma("unroll")                                                       \
            for (int ii = 0; ii < 2; ii++)                                          \
                edreg[ii] = ed_g[(long)(hh*2 + ii) * BN + (long)b * Nsz + m0p + mi];\
        }
    PREFETCH(0);

    short8* hT8 = (short8*)hT;

    for (int t = 0; t < Nsz / TM; t++) {
        // stage h-tile (lane-contiguous b128s, conflict-minimal)
        hT8[j] = hreg[0]; hT8[j+256] = hreg[1]; hT8[j+512] = hreg[2]; hT8[j+768] = hreg[3];
        __syncthreads();

        // snapshot S inputs, then prefetch next tile (overlaps S+A)
        int a_c[4]; float ed_c[2];
        #pragma unroll
        for (int r4 = 0; r4 < 4; r4++) a_c[r4] = areg[r4];
        ed_c[0] = edreg[0]; ed_c[1] = edreg[1];
        if (t + 1 < Nsz / TM) PREFETCH(t + 1);

        // ---- phase S: p = adj ? exp(lrelu(e) - SHIFT) : 0 ; no reductions ----
        #pragma unroll
        for (int r4 = 0; r4 < 4; r4++) {
            const int r = w*4 + r4;
            #pragma unroll
            for (int ii = 0; ii < 2; ii++) {
                const int hx = hh*2 + ii;
                float s = es[r4][ii] + ed_c[ii];
                s = s > 0.f ? s : 0.2f * s;
                float p = (a_c[r4] > 0) ? __expf(s - SHIFT) : 0.f;
                ushort pb = f2bf(p);
                p_bf[(r * Hh + hx) * TM + mi] = pb;
                l_part[r4][ii] += bf2f(pb);   // keep l consistent with quantized p
            }
        }
        __syncthreads();

        // ---- phase A: acc += P(16x32) @ H(32x64) for head w, 4 MFMAs ----
        {
            const short8* pb8 = (const short8*)p_bf;
            short8 af = pb8[(n16 * Hh + w) * 4 + quad];           // A[m=n16][k=quad*8+j]
            #pragma unroll
            for (int c4 = 0; c4 < 4; c4++) {
                short8 bfrag = hT8[(w*64 + c4*16 + n16) * 4 + quad]; // B[k][n=n16]
                acc[c4] = __builtin_amdgcn_mfma_f32_16x16x32_bf16(af, bfrag, acc[c4], 0, 0, 0);
            }
        }
        __syncthreads();
    }

    // ---- epilogue: reduce l over the 32 m-lanes (once), normalize, mean heads ----
    #pragma unroll
    for (int r4 = 0; r4 < 4; r4++)
        #pragma unroll
        for (int ii = 0; ii < 2; ii++) {
            float lp = l_part[r4][ii];
            #pragma unroll
            for (int off = 1; off < 32; off <<= 1) lp += __shfl_xor(lp, off, 64);
            if (mi == 0) l_lds[(w*4 + r4) * Hh + hh*2 + ii] = lp;
        }
    __syncthreads();

    float* o_lds = (float*)hT;   // 16 KB: [head][row16][f64]
    float rinv[4];
    #pragma unroll
    for (int reg = 0; reg < 4; reg++) {
        const int row = quad*4 + reg;                 // C layout: row=(lane>>4)*4+reg
        rinv[reg] = 0.25f / l_lds[row * Hh + w];
    }
    #pragma unroll
    for (int c4 = 0; c4 < 4; c4++)
        #pragma unroll
        for (int reg = 0; reg < 4; reg++) {
            const int row = quad*4 + reg;
            o_lds[(w * TN + row) * FO + c4*16 + n16] = acc[c4][reg] * rinv[reg];
        }
    __syncthreads();

    {
        const int f2 = j & 63, rb = j >> 6;
        #pragma unroll
        for (int i = 0; i < 4; i++) {
            const int r = i*4 + rb;
            const float sum = o_lds[(0*TN + r)*FO + f2] + o_lds[(1*TN + r)*FO + f2]
                            + o_lds[(2*TN + r)*FO + f2] + o_lds[(3*TN + r)*FO + f2];
            out[(rowb + r) * FO + f2] = sum;
        }
    }
}

extern "C" void kernel_launch(void* const* d_in, const int* in_sizes, int n_in,
                              void* d_out, int out_size, void* d_ws, size_t ws_size,
                              hipStream_t stream) {
    const float* x   = (const float*)d_in[0];   // (8,1024,128) f32
    const int*   adj = (const int*)d_in[1];     // (8,1024,1024) i32
    const float* W   = (const float*)d_in[2];   // (128,256) f32
    const float* a   = (const float*)d_in[3];   // (4,128) f32
    float* out = (float*)d_out;                 // (8,1024,64) f32

    // workspace: h_gB bf16 (4MB) | e_src (128KB) | e_dst (128KB), both [h][b*N+n]
    ushort* h_gB = (ushort*)d_ws;
    float*  es_g = (float*)((char*)d_ws + (size_t)BN * COLS * sizeof(ushort));
    float*  ed_g = es_g + (size_t)Hh * BN;

    gat_proj<<<dim3(Bsz * Nsz / 16), dim3(256), 0, stream>>>(x, W, a, h_gB, es_g, ed_g);
    gat_attn<<<dim3(Nsz / TN, Bsz), dim3(256), 0, stream>>>(adj, h_gB, es_g, ed_g, out);
}

// Round 3
// 114.506 us; speedup vs baseline: 4.3947x; 1.1748x over previous
//
#include <hip/hip_runtime.h>
#include <math.h>

#define Bsz 8
#define Nsz 1024
#define FIN 128
#define Hh  4
#define FO  64
#define COLS 256   // Hh*FO
#define TN  16
#define TM  32
#define BN  (Bsz*Nsz)
#define SHIFT 12.0f
#define HSTR 40    // ushort stride per c-row of attn h-tile (32 data + 8 pad -> 2-way banks)
#define PSTR 136   // ushort stride per r-row of p-tile (128 data + 8 pad -> 2-way banks)
#define XSTR 136   // ushort stride per m-row of proj x-tile (128 data + 8 pad)

typedef __attribute__((ext_vector_type(8))) short short8;
typedef __attribute__((ext_vector_type(4))) float f32x4;

static __device__ inline ushort f2bf(float f) {           // RNE float->bf16
    uint u = __float_as_uint(f);
    u += 0x7FFFu + ((u >> 16) & 1u);
    return (ushort)(u >> 16);
}
static __device__ inline float bf2f(ushort h) { return __uint_as_float(((uint)h) << 16); }

// ---------------- prep: Wt[n][k] = bf16(W[k][n]) ----------------
// 8 blocks x 256 thr; thread handles 16 k's of one column.
__global__ __launch_bounds__(256) void gat_prep(const float* __restrict__ W,
                                                ushort* __restrict__ Wt)
{
    const int g = blockIdx.x * 256 + threadIdx.x;   // 0..2047
    const int n = g >> 3, kc = (g & 7) * 16;
    ushort u[16];
    #pragma unroll
    for (int i = 0; i < 16; i++) u[i] = f2bf(W[(kc + i) * COLS + n]);
    int4* dst = (int4*)(Wt + n * FIN + kc);
    dst[0] = ((int4*)u)[0];
    dst[1] = ((int4*)u)[1];
}

// ---------------- Kernel A: h = x@W via MFMA; es/ed from fp32 accumulators ----------------
// grid 512 = (b, 16-row tile), 256 thr. Wave w = head w (cols w*64..w*64+63).
// Per wave: 16 MFMAs (16x16x32), A from LDS x-tile, B from global Wt (L2-hot).
__global__ __launch_bounds__(256) void gat_proj(
    const float* __restrict__ x, const ushort* __restrict__ Wt,
    const float* __restrict__ a, ushort* __restrict__ h_gB,
    float* __restrict__ es_g, float* __restrict__ ed_g)
{
    __shared__ ushort xs[16 * XSTR];   // 4.25 KB
    const int j    = threadIdx.x;
    const int w    = j >> 6, lane = j & 63, quad = lane >> 4, n16 = lane & 15;
    const int b    = blockIdx.x >> 6, mt16 = blockIdx.x & 63;
    const long rowbase = (long)b * Nsz + mt16 * 16;

    // B fragments from global Wt (16 x 16B, issued before barrier; L2-hot)
    short8 bfr[4][4];
    #pragma unroll
    for (int kk = 0; kk < 4; kk++)
        #pragma unroll
        for (int c4 = 0; c4 < 4; c4++)
            bfr[kk][c4] = *(const short8*)(Wt + (w*64 + c4*16 + n16) * FIN + kk*32 + quad*8);

    // stage x tile (16x128) as bf16 into LDS
    {
        const int r = j >> 4, k0 = (j & 15) * 8;
        const float4* g4 = (const float4*)(x + (rowbase + r) * FIN + k0);
        float4 v0 = g4[0], v1 = g4[1];
        ushort u[8] = { f2bf(v0.x), f2bf(v0.y), f2bf(v0.z), f2bf(v0.w),
                        f2bf(v1.x), f2bf(v1.y), f2bf(v1.z), f2bf(v1.w) };
        *(int4*)(xs + r * XSTR + k0) = *(int4*)u;
    }
    __syncthreads();

    f32x4 acc[4];
    #pragma unroll
    for (int c4 = 0; c4 < 4; c4++)
        #pragma unroll
        for (int r = 0; r < 4; r++) acc[c4][r] = 0.f;

    #pragma unroll
    for (int kk = 0; kk < 4; kk++) {
        short8 af = *(const short8*)(xs + n16 * XSTR + kk*32 + quad*8);  // A[m=n16][k]
        #pragma unroll
        for (int c4 = 0; c4 < 4; c4++)
            acc[c4] = __builtin_amdgcn_mfma_f32_16x16x32_bf16(af, bfr[kk][c4], acc[c4], 0, 0, 0);
    }

    // ---- h_gB store: [b][mt=row/32][c][k=row%32] bf16 ----
    const int mtile = mt16 >> 1;
    const int kbase = (mt16 & 1) * 16 + quad * 4;      // C row = quad*4+reg
    #pragma unroll
    for (int c4 = 0; c4 < 4; c4++) {
        uint2 pk;
        pk.x = (uint)f2bf(acc[c4][0]) | ((uint)f2bf(acc[c4][1]) << 16);
        pk.y = (uint)f2bf(acc[c4][2]) | ((uint)f2bf(acc[c4][3]) << 16);
        const int c = w*64 + c4*16 + n16;
        *(uint2*)(h_gB + (((long)(b*32 + mtile) * COLS + c) * 32 + kbase)) = pk;
    }

    // ---- es/ed from fp32 accumulators: reduce over head's 64 cols ----
    float aS[4], aD[4];
    #pragma unroll
    for (int c4 = 0; c4 < 4; c4++) {
        aS[c4] = a[w * (2*FO) + c4*16 + n16];
        aD[c4] = a[w * (2*FO) + FO + c4*16 + n16];
    }
    #pragma unroll
    for (int reg = 0; reg < 4; reg++) {
        float ps = 0.f, pd = 0.f;
        #pragma unroll
        for (int c4 = 0; c4 < 4; c4++) {
            ps = fmaf(acc[c4][reg], aS[c4], ps);
            pd = fmaf(acc[c4][reg], aD[c4], pd);
        }
        #pragma unroll
        for (int off = 1; off < 16; off <<= 1) {       // reduce across n16 lanes
            ps += __shfl_xor(ps, off, 64);
            pd += __shfl_xor(pd, off, 64);
        }
        if (n16 == 0) {
            const long row = rowbase + quad*4 + reg;
            es_g[(long)w * BN + row] = ps;
            ed_g[(long)w * BN + row] = pd;
        }
    }
}

// ---------------- Kernel B: double-buffered, one barrier/tile ----------------
// grid (64, 8), 256 thr. Phase S writes p(t+1) from register-prefetched adj/ed;
// Phase A consumes buffers (t&1). Padded LDS strides -> <=2-way bank conflicts.
__global__ __launch_bounds__(256, 3) void gat_attn(
    const int* __restrict__ adj, const ushort* __restrict__ h_gB,
    const float* __restrict__ es_g, const float* __restrict__ ed_g,
    float* __restrict__ out)
{
    __shared__ ushort hT[2][COLS * HSTR];   // 2 x 20 KB
    __shared__ ushort pT[2][TN * PSTR];     // 2 x 4.25 KB
    __shared__ float  l_lds[TN * Hh];

    const int j    = threadIdx.x;
    const int w    = j >> 6, lane = j & 63, quad = lane >> 4, n16 = lane & 15;
    const int mi   = lane & 31, hh = lane >> 5;
    const int b    = blockIdx.y;
    const int n0   = blockIdx.x * TN;
    const long rowb = (long)b * Nsz + n0;

    float es[4][2];
    #pragma unroll
    for (int r4 = 0; r4 < 4; r4++)
        #pragma unroll
        for (int ii = 0; ii < 2; ii++)
            es[r4][ii] = es_g[(long)(hh*2 + ii) * BN + rowb + w*4 + r4];

    f32x4 acc[4];
    #pragma unroll
    for (int c4 = 0; c4 < 4; c4++)
        #pragma unroll
        for (int r = 0; r < 4; r++) acc[c4][r] = 0.f;

    float l_part[4][2];
    #pragma unroll
    for (int r4 = 0; r4 < 4; r4++) { l_part[r4][0] = 0.f; l_part[r4][1] = 0.f; }

    short8 hreg[4]; int areg[4]; float edreg[2];
    const short8* hb8 = (const short8*)h_gB;

#define PREFETCH(t) {                                                           \
    const short8* g = hb8 + (long)(b*32 + (t)) * 1024;                          \
    hreg[0] = g[j]; hreg[1] = g[j+256]; hreg[2] = g[j+512]; hreg[3] = g[j+768]; \
    const int m0p = (t) * TM;                                                   \
    _Pragma("unroll")                                                           \
    for (int r4 = 0; r4 < 4; r4++)                                              \
        areg[r4] = adj[(rowb + w*4 + r4) * (long)Nsz + m0p + mi];               \
    _Pragma("unroll")                                                           \
    for (int ii = 0; ii < 2; ii++)                                              \
        edreg[ii] = ed_g[(long)(hh*2 + ii) * BN + (long)b * Nsz + m0p + mi]; }

#define STAGE(buf) {                                                            \
    _Pragma("unroll")                                                           \
    for (int i = 0; i < 4; i++) {                                               \
        const int s = j + 256*i;                                                \
        *(short8*)(&hT[buf][(s >> 2) * HSTR + (s & 3) * 8]) = hreg[i]; } }

#define PHASE_S(buf) {                                                          \
    _Pragma("unroll")                                                           \
    for (int r4 = 0; r4 < 4; r4++) {                                            \
        _Pragma("unroll")                                                       \
        for (int ii = 0; ii < 2; ii++) {                                        \
            float s = es[r4][ii] + edreg[ii];                                   \
            s = fmaxf(s, 0.2f * s);                                             \
            float p = (areg[r4] > 0) ? __expf(s - SHIFT) : 0.f;                 \
            ushort pb = f2bf(p);                                                \
            pT[buf][(w*4 + r4) * PSTR + (hh*2 + ii) * TM + mi] = pb;            \
            l_part[r4][ii] += bf2f(pb); } } }

#define PHASE_A(buf) {                                                          \
    short8 af = *(const short8*)(&pT[buf][n16 * PSTR + w * TM + quad * 8]);     \
    _Pragma("unroll")                                                           \
    for (int c4 = 0; c4 < 4; c4++) {                                            \
        short8 bfv = *(const short8*)(&hT[buf][(w*64 + c4*16 + n16) * HSTR + quad * 8]); \
        acc[c4] = __builtin_amdgcn_mfma_f32_16x16x32_bf16(af, bfv, acc[c4], 0, 0, 0); } }

    PREFETCH(0);
    STAGE(0); PHASE_S(0);
    PREFETCH(1);
    __syncthreads();

    for (int t = 0; t < Nsz / TM; t++) {
        const int cur = t & 1;
        if (t < Nsz / TM - 1) {
            STAGE(cur ^ 1);
            PHASE_S(cur ^ 1);
            if (t < Nsz / TM - 2) PREFETCH(t + 2);
        }
        PHASE_A(cur);
        __syncthreads();   // protects hT/pT[cur^1] writes (read by A(t-1)) and publishes t+1
    }

    // ---- epilogue: reduce l over 32 m-lanes once, normalize, mean heads ----
    #pragma unroll
    for (int r4 = 0; r4 < 4; r4++)
        #pragma unroll
        for (int ii = 0; ii < 2; ii++) {
            float lp = l_part[r4][ii];
            #pragma unroll
            for (int off = 1; off < 32; off <<= 1) lp += __shfl_xor(lp, off, 64);
            if (mi == 0) l_lds[(w*4 + r4) * Hh + hh*2 + ii] = lp;
        }
    __syncthreads();

    float* o_lds = (float*)&hT[0][0];   // 16 KB, disjoint from hT[1] (read by A(31))
    float rinv[4];
    #pragma unroll
    for (int reg = 0; reg < 4; reg++)
        rinv[reg] = 0.25f / l_lds[(quad*4 + reg) * Hh + w];
    #pragma unroll
    for (int c4 = 0; c4 < 4; c4++)
        #pragma unroll
        for (int reg = 0; reg < 4; reg++)
            o_lds[(w * TN + quad*4 + reg) * FO + c4*16 + n16] = acc[c4][reg] * rinv[reg];
    __syncthreads();

    {
        const int f2 = j & 63, rb = j >> 6;
        #pragma unroll
        for (int i = 0; i < 4; i++) {
            const int r = i*4 + rb;
            const float sum = o_lds[(0*TN + r)*FO + f2] + o_lds[(1*TN + r)*FO + f2]
                            + o_lds[(2*TN + r)*FO + f2] + o_lds[(3*TN + r)*FO + f2];
            out[(rowb + r) * FO + f2] = sum;
        }
    }
#undef PREFETCH
#undef STAGE
#undef PHASE_S
#undef PHASE_A
}

extern "C" void kernel_launch(void* const* d_in, const int* in_sizes, int n_in,
                              void* d_out, int out_size, void* d_ws, size_t ws_size,
                              hipStream_t stream) {
    const float* x   = (const float*)d_in[0];   // (8,1024,128) f32
    const int*   adj = (const int*)d_in[1];     // (8,1024,1024) i32
    const float* W   = (const float*)d_in[2];   // (128,256) f32
    const float* a   = (const float*)d_in[3];   // (4,128) f32
    float* out = (float*)d_out;                 // (8,1024,64) f32

    // ws: Wt bf16 (64KB) | h_gB bf16 (4MB) | es (128KB) | ed (128KB)
    ushort* Wt   = (ushort*)d_ws;
    ushort* h_gB = Wt + (size_t)COLS * FIN;
    float*  es_g = (float*)(h_gB + (size_t)BN * COLS);
    float*  ed_g = es_g + (size_t)Hh * BN;

    gat_prep<<<dim3(8),            dim3(256), 0, stream>>>(W, Wt);
    gat_proj<<<dim3(Bsz*Nsz/16),   dim3(256), 0, stream>>>(x, Wt, a, h_gB, es_g, ed_g);
    gat_attn<<<dim3(Nsz/TN, Bsz),  dim3(256), 0, stream>>>(adj, h_gB, es_g, ed_g, out);
}